// Round 2
// 341.016 us; speedup vs baseline: 1.0132x; 1.0132x over previous
//
#include <hip/hip_runtime.h>
#include <hip/hip_bf16.h>
#include <stdint.h>

#define EMB 1024
#define HEADS 16
#define HDIM 64
#define BATCH 4
#define SEQ 2048
#define MTOT (BATCH * SEQ) /* 8192 */

typedef unsigned short u16;
typedef __attribute__((ext_vector_type(8))) short bf16x8;
typedef __attribute__((ext_vector_type(4))) float f32x4;

__device__ inline u16 f2bf(float f) {
    uint32_t u = __builtin_bit_cast(uint32_t, f);
    u += 0x7fffu + ((u >> 16) & 1u);  // RNE; inputs are finite
    return (u16)(u >> 16);
}

// pack 2 f32 -> 2 bf16 (round-half-up; p>=0 smooth values, bias negligible)
__device__ inline uint32_t pk2bf(float a, float b) {
    uint32_t ua = __builtin_bit_cast(uint32_t, a) + 0x8000u;
    uint32_t ub = __builtin_bit_cast(uint32_t, b) + 0x8000u;
    return (ua >> 16) | (ub & 0xffff0000u);
}

__device__ inline f32x4 mfma16(bf16x8 a, bf16x8 b, f32x4 c) {
    return __builtin_amdgcn_mfma_f32_16x16x32_bf16(a, b, c, 0, 0, 0);
}

#define GLDS16(gp, lp)                                                        \
    __builtin_amdgcn_global_load_lds(                                         \
        (const __attribute__((address_space(1))) void*)(gp),                  \
        (__attribute__((address_space(3))) void*)(lp), 16, 0, 0)

// ------ mask compaction: per batch, list of active key positions ----------
// cnt[b] = #active; idx[b][j] = source row of compacted key j (j < cnt).
__global__ void mask_compact(const int* __restrict__ mask,
                             int* __restrict__ cnt, int* __restrict__ idx) {
    __shared__ int ps[256];
    const int b = blockIdx.x, tid = threadIdx.x;
    const int* mp = mask + (size_t)b * SEQ;
    int m[8], s = 0;
#pragma unroll
    for (int e = 0; e < 8; ++e) {
        m[e] = mp[tid * 8 + e] ? 1 : 0;
        s += m[e];
    }
    ps[tid] = s;
    __syncthreads();
    for (int off = 1; off < 256; off <<= 1) {
        int v = (tid >= off) ? ps[tid - off] : 0;
        __syncthreads();
        if (tid >= off) ps[tid] += v;
        __syncthreads();
    }
    const int total = ps[255];
    int r = ps[tid] - s;  // exclusive prefix
#pragma unroll
    for (int e = 0; e < 8; ++e)
        if (m[e]) idx[b * SEQ + r++] = tid * 8 + e;
    if (tid == 0) cnt[b] = total;
}

// ------ gather active rows + cast f32->bf16 (key/value inputs) ------------
// dst row (b, j): j < cnt -> src row idx[b][j]; cnt<=j<cntp -> zeros;
// j >= cntp -> untouched (never read downstream).
__global__ void gather_cast(const float* __restrict__ src,
                            const int* __restrict__ idx,
                            const int* __restrict__ cnt,
                            u16* __restrict__ dst) {
    const int row = blockIdx.x;  // 0..MTOT-1
    const int b = row >> 11, j = row & (SEQ - 1);
    const int cn = cnt[b];
    const int cp = (cn + 127) & ~127;
    if (j >= cp) return;
    const int c4 = threadIdx.x;  // 0..255 = EMB/4
    float4 v = {0.f, 0.f, 0.f, 0.f};
    if (j < cn) {
        const int srow = idx[b * SEQ + j];
        v = ((const float4*)(src + (size_t)(b * SEQ + srow) * EMB))[c4];
    }
    ushort4 o;
    o.x = f2bf(v.x); o.y = f2bf(v.y); o.z = f2bf(v.z); o.w = f2bf(v.w);
    ((ushort4*)(dst + (size_t)row * EMB))[c4] = o;
}

// ---------------- cast f32 -> bf16 (vectorized) ----------------
__global__ void cast_f32_bf16(const float* __restrict__ src,
                              u16* __restrict__ dst, int n4) {
    int i = blockIdx.x * blockDim.x + threadIdx.x;
    if (i >= n4) return;
    float4 v = ((const float4*)src)[i];
    ushort4 o;
    o.x = f2bf(v.x); o.y = f2bf(v.y); o.z = f2bf(v.z); o.w = f2bf(v.w);
    ((ushort4*)dst)[i] = o;
}

// ---------------- transpose + cast W (EMB x EMB): Wt[n][k] = W[k][n] -------
__global__ void transpose_cast(const float* __restrict__ W,
                               u16* __restrict__ Wt) {
    __shared__ u16 T[64][65];
    const int kb = blockIdx.y * 64, nb = blockIdx.x * 64;
    const int tr = threadIdx.x >> 4;         // 0..15
    const int tc = (threadIdx.x & 15) * 4;   // 0..60
#pragma unroll
    for (int j = 0; j < 4; ++j) {
        int r = tr + j * 16;
        float4 v = *(const float4*)&W[(size_t)(kb + r) * EMB + nb + tc];
        T[tc + 0][r] = f2bf(v.x);
        T[tc + 1][r] = f2bf(v.y);
        T[tc + 2][r] = f2bf(v.z);
        T[tc + 3][r] = f2bf(v.w);
    }
    __syncthreads();
#pragma unroll
    for (int j = 0; j < 4; ++j) {
        int rr = tr + j * 16;
        ushort4 o;
        o.x = T[rr][tc]; o.y = T[rr][tc + 1];
        o.z = T[rr][tc + 2]; o.w = T[rr][tc + 3];
        *(ushort4*)&Wt[(size_t)(nb + rr) * EMB + kb + tc] = o;
    }
}

// ------- transpose V per head, PV-permuted: Vp[b][s][h*64+d] -> Vt --------
// Within each 32-key group, key k (quad=(k&15)>>2, r=k&3, half=k>>4) is
// stored at position quad*8 + r + 4*half -> PV A-operand is one b128 read.
// Early-exits blocks beyond the batch's padded active-key count.
__global__ void transpose_v(const u16* __restrict__ Vp, u16* __restrict__ Vt,
                            const int* __restrict__ cnt) {
    __shared__ u16 T[64][65];
    const int h = blockIdx.x;           // 0..15 (one head = 64 cols)
    const int b = blockIdx.y >> 5;      // /(SEQ/64)
    const int s0 = (blockIdx.y & 31) * 64;
    const int cp = (cnt[b] + 127) & ~127;
    if (s0 >= cp) return;
    const int tr = threadIdx.x >> 3;    // 0..31
    const int tc = (threadIdx.x & 7) * 8;
#pragma unroll
    for (int j = 0; j < 2; ++j) {
        int sr = tr + j * 32;
        uint4 v = *(const uint4*)&Vp[(size_t)(b * SEQ + s0 + sr) * EMB +
                                     h * 64 + tc];
        const u16* p = (const u16*)&v;
#pragma unroll
        for (int e = 0; e < 8; ++e) T[tc + e][sr] = p[e];
    }
    __syncthreads();
#pragma unroll
    for (int j = 0; j < 2; ++j) {
        int d = tr + j * 32;
        u16 tmp[8];
#pragma unroll
        for (int e = 0; e < 8; ++e) tmp[e] = T[d][tc + e];
        const int base32 = s0 + (tc & 32);
        const int p0 = ((tc & 8) << 1) + ((tc & 16) >> 2);
        const size_t rowoff =
            ((size_t)(b * HEADS + h) * HDIM + d) * SEQ;
        *(uint2*)&Vt[rowoff + base32 + p0] = *(const uint2*)&tmp[0];
        *(uint2*)&Vt[rowoff + base32 + p0 + 8] = *(const uint2*)&tmp[4];
    }
}

// ------- GEMM: C[M][N] = (A[M][K] @ Bt[N][K]^T + bias) * scale -------------
// Optional cnt: M is batch-blocked (SEQ rows/batch); blocks whose 128-row
// tile lies beyond the batch's padded active count exit immediately.
template <bool OUT_BF16>
__global__ __launch_bounds__(256, 2) void gemm_bt(
    const u16* __restrict__ A, const u16* __restrict__ Bt,
    const float* __restrict__ bias, void* __restrict__ C,
    int M, int N, int K, float scale, const int* __restrict__ cnt) {
    __shared__ __align__(16) u16 As[128 * 32];
    __shared__ __align__(16) u16 Bs[128 * 32];
    const int m0 = blockIdx.y * 128, n0 = blockIdx.x * 128;
    if (cnt) {
        const int bb = m0 >> 11;
        const int cp = (cnt[bb] + 127) & ~127;
        if ((m0 & (SEQ - 1)) >= cp) return;
    }
    const int tid = threadIdx.x;
    const int w = tid >> 6, l = tid & 63;
    const int quad = l >> 4, l16 = l & 15;
    const int wm = (w >> 1) * 64, wn = (w & 1) * 64;

    f32x4 acc[4][4];
#pragma unroll
    for (int i = 0; i < 4; ++i)
#pragma unroll
        for (int j = 0; j < 4; ++j) acc[i][j] = (f32x4){0.f, 0.f, 0.f, 0.f};

    for (int k0 = 0; k0 < K; k0 += 32) {
        __syncthreads();
#pragma unroll
        for (int i = 0; i < 2; ++i) {
            int c = (w * 2 + i) * 64 + l;            // lds chunk, lane-contig
            int r = c >> 2;
            int sc = (c & 3) ^ ((r >> 1) & 3);       // global chunk (swizzle)
            GLDS16(A + (size_t)(m0 + r) * K + k0 + sc * 8, &As[c * 8]);
            GLDS16(Bt + (size_t)(n0 + r) * K + k0 + sc * 8, &Bs[c * 8]);
        }
        __syncthreads();
        bf16x8 af[4], bfr[4];
#pragma unroll
        for (int mt = 0; mt < 4; ++mt) {
            int ra = wm + mt * 16 + l16;
            af[mt] = *(const bf16x8*)&As[ra * 32 +
                                         ((quad ^ ((ra >> 1) & 3)) * 8)];
        }
#pragma unroll
        for (int nt = 0; nt < 4; ++nt) {
            int rb = wn + nt * 16 + l16;
            bfr[nt] = *(const bf16x8*)&Bs[rb * 32 +
                                          ((quad ^ ((rb >> 1) & 3)) * 8)];
        }
#pragma unroll
        for (int mt = 0; mt < 4; ++mt)
#pragma unroll
            for (int nt = 0; nt < 4; ++nt)
                acc[mt][nt] = mfma16(af[mt], bfr[nt], acc[mt][nt]);
    }

#pragma unroll
    for (int mt = 0; mt < 4; ++mt) {
#pragma unroll
        for (int nt = 0; nt < 4; ++nt) {
            int col = n0 + wn + nt * 16 + l16;
            float bv = bias[col];
#pragma unroll
            for (int r = 0; r < 4; ++r) {
                int row = m0 + wm + mt * 16 + quad * 4 + r;
                float v = (acc[mt][nt][r] + bv) * scale;
                if (OUT_BF16)
                    ((u16*)C)[(size_t)row * N + col] = f2bf(v);
                else
                    ((float*)C)[(size_t)row * N + col] = v;
            }
        }
    }
}

// ------ flash attention over COMPACTED keys: Q-tile 128, S^T scores -------
// Q is pre-scaled by 1/sqrt(d)*log2(e) in its GEMM epilogue, so the score
// path is exp2(s) directly; only the LAST key tile has pad keys, handled by
// a register compare vs cnt (-30000 bias -> p=0). Row-sum l accumulated on
// the MFMA pipe via an all-ones A fragment (D[i][j] = sum_k P^T[k][j],
// replicated across rows -> no shuffles). Wave owns 32 q rows; K/V
// fragments shared across both 16-row groups; V PV-permuted (b128 A-op);
// K/V double-buffered, one barrier/iter.
__global__ __launch_bounds__(256, 2) void attn_kernel(
    const u16* __restrict__ Qp, const u16* __restrict__ Kp,
    const u16* __restrict__ Vt, const int* __restrict__ cnt,
    u16* __restrict__ attnb) {
    __shared__ __align__(16) u16 Ks[2][128 * 64];    // 32 KB
    __shared__ __align__(16) u16 Vts[2][64 * 128];   // 32 KB -> 64 KB total

    const int tid = threadIdx.x;
    const int w = tid >> 6, l = tid & 63;
    const int quad = l >> 4, l16 = l & 15;

    const int nqb = SEQ / 128;  // 16
    const int qb = blockIdx.x % nqb;
    const int bh = blockIdx.x / nqb;
    const int b = bh / HEADS, h = bh % HEADS;
    const int q0 = qb * 128;
    const size_t head_off = (size_t)b * SEQ * EMB + (size_t)h * HDIM;
    const size_t vt_off = (size_t)bh * HDIM * SEQ;

    const int cn = cnt[b];
    const int ntile = ((cn + 127) & ~127) >> 7;  // >=1 (mask has actives)

    auto stageKV = [&](int buf, int t) {
#pragma unroll
        for (int i = 0; i < 4; ++i) {
            int c = (w * 4 + i) * 64 + l;
            int r = c >> 3;
            int sc = (c & 7) ^ (r & 7);
            GLDS16(Kp + head_off + (size_t)(t * 128 + r) * EMB + sc * 8,
                   &Ks[buf][c * 8]);
        }
#pragma unroll
        for (int i = 0; i < 4; ++i) {
            int c = (w * 4 + i) * 64 + l;
            int r = c >> 4;
            int sc = (c & 15) ^ (r & 15);
            GLDS16(Vt + vt_off + (size_t)r * SEQ + t * 128 + sc * 8,
                   &Vts[buf][c * 8]);
        }
    };

    // Q fragments direct global->VGPR (one-time)
    bf16x8 bq[2][2];
#pragma unroll
    for (int g = 0; g < 2; ++g) {
        const u16* qrow =
            Qp + head_off + (size_t)(q0 + w * 32 + g * 16 + l16) * EMB;
        bq[g][0] = *(const bf16x8*)(qrow + quad * 8);
        bq[g][1] = *(const bf16x8*)(qrow + 32 + quad * 8);
    }

    // all-ones bf16 A fragment for row-sum MFMA
    bf16x8 ones;
#pragma unroll
    for (int e = 0; e < 8; ++e) ones[e] = (short)0x3f80;

    // prefetch tile 0
    stageKV(0, 0);
    __syncthreads();  // KV(0) visible

    f32x4 OA[4], OB[4];
#pragma unroll
    for (int i = 0; i < 4; ++i) {
        OA[i] = (f32x4){0.f, 0.f, 0.f, 0.f};
        OB[i] = (f32x4){0.f, 0.f, 0.f, 0.f};
    }
    f32x4 LA = (f32x4){0.f, 0.f, 0.f, 0.f};
    f32x4 LB = (f32x4){0.f, 0.f, 0.f, 0.f};

    auto tilebody = [&](int t, bool last) {
        const int cur = t & 1;
        if (!last) stageKV(cur ^ 1, t + 1);  // async prefetch
        const u16* ksb = Ks[cur];
        const u16* vsb = Vts[cur];

        // S^T + exp + pack, both q groups sharing K fragments
        uint32_t pk[2][8][2];
#pragma unroll
        for (int nt = 0; nt < 8; ++nt) {
            int rk = nt * 16 + l16;
            bf16x8 ka0 =
                *(const bf16x8*)&ksb[rk * 64 + ((quad ^ (rk & 7)) * 8)];
            bf16x8 ka1 =
                *(const bf16x8*)&ksb[rk * 64 + (((quad + 4) ^ (rk & 7)) * 8)];
#pragma unroll
            for (int g = 0; g < 2; ++g) {
                f32x4 s = (f32x4){0.f, 0.f, 0.f, 0.f};
                s = mfma16(ka0, bq[g][0], s);  // A=K, B=Q -> S^T
                s = mfma16(ka1, bq[g][1], s);
                f32x4 p;
                if (last) {
                    const int kb = t * 128 + nt * 16 + quad * 4;
#pragma unroll
                    for (int r = 0; r < 4; ++r)
                        p[r] = __builtin_amdgcn_exp2f(
                            (kb + r < cn) ? s[r] : -30000.f);
                } else {
#pragma unroll
                    for (int r = 0; r < 4; ++r)
                        p[r] = __builtin_amdgcn_exp2f(s[r]);
                }
                pk[g][nt][0] = pk2bf(p[0], p[1]);
                pk[g][nt][1] = pk2bf(p[2], p[3]);
            }
        }

        // O^T += V^T·P^T, V fragments shared across both q groups;
        // l += 1^T·P^T on the MFMA pipe
#pragma unroll
        for (int i = 0; i < 4; ++i) {
            union { bf16x8 v; uint32_t u[4]; } bpA, bpB;
            bpA.u[0] = pk[0][2 * i][0];
            bpA.u[1] = pk[0][2 * i][1];
            bpA.u[2] = pk[0][2 * i + 1][0];
            bpA.u[3] = pk[0][2 * i + 1][1];
            bpB.u[0] = pk[1][2 * i][0];
            bpB.u[1] = pk[1][2 * i][1];
            bpB.u[2] = pk[1][2 * i + 1][0];
            bpB.u[3] = pk[1][2 * i + 1][1];
            LA = mfma16(ones, bpA.v, LA);
            LB = mfma16(ones, bpB.v, LB);
#pragma unroll
            for (int dt = 0; dt < 4; ++dt) {
                int vd = dt * 16 + l16;
                bf16x8 ap = *(const bf16x8*)&vsb[vd * 128 +
                                                 (((4 * i + quad) ^ (vd & 15)) *
                                                  8)];
                OA[dt] = mfma16(ap, bpA.v, OA[dt]);
                OB[dt] = mfma16(ap, bpB.v, OB[dt]);
            }
        }

        __syncthreads();  // drains own DMA+ds_reads, then syncs (dbuf safety)
    };

    for (int t = 0; t < ntile - 1; ++t) tilebody(t, false);
    tilebody(ntile - 1, true);

    // epilogue: O[q][d] = O^T[d][q]/l; lane: q=l16, d=dt*16+quad*4+r
    // LA/LB rows are all equal (A=ones), so l = LA[0]/LB[0].
#pragma unroll
    for (int g = 0; g < 2; ++g) {
        float inv = 1.0f / (g == 0 ? LA[0] : LB[0]);
        const f32x4* O = (g == 0) ? OA : OB;
        const int orow = q0 + w * 32 + g * 16 + l16;
#pragma unroll
        for (int dt = 0; dt < 4; ++dt) {
            ushort4 o;
            o.x = f2bf(O[dt][0] * inv);
            o.y = f2bf(O[dt][1] * inv);
            o.z = f2bf(O[dt][2] * inv);
            o.w = f2bf(O[dt][3] * inv);
            *(uint2*)&attnb[head_off + (size_t)orow * EMB + dt * 16 +
                            quad * 4] = *(uint2*)&o;
        }
    }
}

extern "C" void kernel_launch(void* const* d_in, const int* in_sizes, int n_in,
                              void* d_out, int out_size, void* d_ws,
                              size_t ws_size, hipStream_t stream) {
    const float* query = (const float*)d_in[0];
    const float* key = (const float*)d_in[1];
    const float* value = (const float*)d_in[2];
    const int* mask = (const int*)d_in[3];
    const float* Wq = (const float*)d_in[4];
    const float* bq = (const float*)d_in[5];
    const float* Wk = (const float*)d_in[6];
    const float* bk = (const float*)d_in[7];
    const float* Wv = (const float*)d_in[8];
    const float* bv = (const float*)d_in[9];
    const float* Wo = (const float*)d_in[10];
    const float* bo = (const float*)d_in[11];

    char* ws = (char*)d_ws;
    const size_t MB = 1ull << 20;
    u16* xq = (u16*)(ws + 0 * MB);     // 16 MB; dead after Q-GEMM -> reused as Vt
    u16* xk = (u16*)(ws + 16 * MB);    // compacted key rows (bf16)
    u16* xv = (u16*)(ws + 32 * MB);    // compacted value rows (bf16)
    u16* Wqt = (u16*)(ws + 48 * MB);   // 2 MB each
    u16* Wkt = (u16*)(ws + 50 * MB);
    u16* Wvt = (u16*)(ws + 52 * MB);
    u16* Wot = (u16*)(ws + 54 * MB);
    u16* Qp = (u16*)(ws + 56 * MB);
    u16* Kp = (u16*)(ws + 72 * MB);
    u16* Vp = (u16*)(ws + 88 * MB);
    u16* attnb = (u16*)(ws + 104 * MB);  // total 120 MB
    u16* Vt = xq;                        // Vt[b][h][d][s-permuted], 16 MB

    // compaction scratch lives in d_out (fully overwritten by O-GEMM later)
    int* cnt = (int*)d_out;                      // 4 ints
    int* idx = (int*)d_out + 64;                 // MTOT ints

    mask_compact<<<BATCH, 256, 0, stream>>>(mask, cnt, idx);

    const int n4 = MTOT * EMB / 4;
    cast_f32_bf16<<<(n4 + 255) / 256, 256, 0, stream>>>(query, xq, n4);
    gather_cast<<<MTOT, 256, 0, stream>>>(key, idx, cnt, xk);
    gather_cast<<<MTOT, 256, 0, stream>>>(value, idx, cnt, xv);

    dim3 tgrid(EMB / 64, EMB / 64);
    transpose_cast<<<tgrid, 256, 0, stream>>>(Wq, Wqt);
    transpose_cast<<<tgrid, 256, 0, stream>>>(Wk, Wkt);
    transpose_cast<<<tgrid, 256, 0, stream>>>(Wv, Wvt);
    transpose_cast<<<tgrid, 256, 0, stream>>>(Wo, Wot);

    const float c2 = 0.125f * 1.44269504f;  // 1/sqrt(64) * log2(e)
    dim3 ggrid(EMB / 128, MTOT / 128);  // (8, 64)
    gemm_bt<true><<<ggrid, 256, 0, stream>>>(xq, Wqt, bq, Qp, MTOT, EMB, EMB,
                                             c2, nullptr);
    gemm_bt<true><<<ggrid, 256, 0, stream>>>(xk, Wkt, bk, Kp, MTOT, EMB, EMB,
                                             1.0f, cnt);
    gemm_bt<true><<<ggrid, 256, 0, stream>>>(xv, Wvt, bv, Vp, MTOT, EMB, EMB,
                                             1.0f, cnt);

    // V^T once per element, PV-permuted key order (compacted key space)
    transpose_v<<<dim3(HEADS, MTOT / 64), 256, 0, stream>>>(Vp, Vt, cnt);

    attn_kernel<<<BATCH * HEADS * (SEQ / 128), 256, 0, stream>>>(Qp, Kp, Vt,
                                                                 cnt, attnb);

    gemm_bt<false><<<ggrid, 256, 0, stream>>>(attnb, Wot, bo, d_out, MTOT, EMB,
                                              EMB, 1.0f, nullptr);
}